// Round 1
// baseline (261.607 us; speedup 1.0000x reference)
//
#include <hip/hip_runtime.h>
#include <stdint.h>

// ---------------------------------------------------------------------------
// Fused LSTM cell: gates = x@Wx + h@Wh + (bx+bh); c = sig(f)*C + sig(i)*tanh(g)
//                  h = sig(o)*tanh(c)
// B=131072, IN=100, H=256. All fp32 in/out; GEMM in bf16 MFMA (32x32x16).
//
// Block: 512 thr (8 waves), tile = 256 rows x 256 gate-cols (64 H-cols).
// Gate-col interleave: local col c -> gate=(c>>5)&3, hcol=(c>>7)*32+(c&31),
// so each wave (wc half of 128 cols) owns all 4 gates of 32 H-cols and the
// epilogue combine is purely lane-local.
// K loop: 12 stages of BK=32 (stages 0-3: x/Wx, k padded 100->128 w/ zeros;
// stages 4-11: h/Wh). Double-buffered LDS, reg-staged fp32->bf16 convert.
// ---------------------------------------------------------------------------

typedef short   bf16x8 __attribute__((ext_vector_type(8)));
typedef unsigned short u16x8 __attribute__((ext_vector_type(8)));
typedef float   f32x16 __attribute__((ext_vector_type(16)));

#define HDIM   256
#define INDIM  100
#define NROWS  131072
#define KPAD   40          // 32 bf16 + pad -> 80B row stride, 16B aligned
#define NSTAGE 12
#define LDSOFF (256 * KPAD)  // one buffer = 256 rows/cols x KPAD ushorts

__device__ __forceinline__ float fexp(float x) {
  return __builtin_amdgcn_exp2f(x * 1.44269504088896340736f);
}
__device__ __forceinline__ float frcp(float x) { return __builtin_amdgcn_rcpf(x); }
__device__ __forceinline__ float sigm(float x) { return frcp(1.0f + fexp(-x)); }
__device__ __forceinline__ float tanh_fast(float x) {
  return 1.0f - 2.0f * frcp(1.0f + fexp(2.0f * x));
}
__device__ __forceinline__ unsigned short f2bf(float f) {
  union { float f; uint32_t u; } v; v.f = f;
  uint32_t r = (v.u + 0x7FFFu + ((v.u >> 16) & 1u)) >> 16;  // RNE
  return (unsigned short)r;
}

__global__ __launch_bounds__(512, 2)
void lstm_fused(const float* __restrict__ X, const float* __restrict__ Cin,
                const float* __restrict__ Hin, const float* __restrict__ Wxp,
                const float* __restrict__ Whp, const float* __restrict__ bxp,
                const float* __restrict__ bhp, float* __restrict__ out)
{
  // A dbuf (2x 256x40) then B dbuf (2x 256x40), ushort bf16 bits = 80 KiB
  __shared__ unsigned short smem[4 * 256 * KPAD];

  const int tid  = threadIdx.x;
  // XCD-bijective swizzle: nwg=2048 (%8==0). XCD k gets a contiguous M-range;
  // the 4 N-sibling blocks of an M-tile stay on one XCD (L2 reuse of x/h).
  const int orig = blockIdx.x;                 // 0..2047
  const int lg   = ((orig & 7) << 8) + (orig >> 3);
  const int mt   = lg >> 2;                    // M tile 0..511 (256 rows each)
  const int nt   = lg & 3;                     // N tile 0..3   (64 H-cols each)

  const int lane = tid & 63;
  const int l31  = lane & 31;
  const int hl   = lane >> 5;                  // k-half within wave
  const int wid  = tid >> 6;                   // 0..7
  const int wr   = wid >> 1;                   // 0..3: row group (64 rows)
  const int wc   = wid & 1;                    // 0..1: col half (32 H-cols)

  // ---- bias preload (gate g, H-col ch) ----
  const int ch = nt * 64 + wc * 32 + l31;      // H column this lane owns
  float bias[4];
#pragma unroll
  for (int g = 0; g < 4; ++g)
    bias[g] = bxp[g * HDIM + ch] + bhp[g * HDIM + ch];

  // ---- staging thread mapping ----
  const int arow  = tid >> 1;                  // 0..255 (A row)
  const int aks   = (tid & 1) * 16;            // k sub-offset 0/16
  const int bcol  = tid & 255;                 // local B col 0..255
  const int bkh   = tid >> 8;                  // 0..1 (k half)
  const int bgate = (bcol >> 5) & 3;
  const int bwc   = bcol >> 7;
  const int bgcol = bgate * HDIM + nt * 64 + bwc * 32 + (bcol & 31); // 0..1023

  f32x16 acc[2][4];
#pragma unroll
  for (int m = 0; m < 2; ++m)
#pragma unroll
    for (int n = 0; n < 4; ++n)
#pragma unroll
      for (int e = 0; e < 16; ++e) acc[m][n][e] = 0.0f;

  float av[16];  // A stage regs (16 fp32)
  float bv[16];  // B stage regs (16 fp32)

  auto stage_load = [&](int s) {
    const bool  xph  = (s < 4);
    const float* Asrc = xph ? X : Hin;
    const float* W    = xph ? Wxp : Whp;
    const int    lda  = xph ? INDIM : HDIM;    // also the valid K extent
    const int    kb   = xph ? s * 32 : (s - 4) * 32;
    // A: 256 rows x 32 k, 2 threads/row, 4x float4 each (guarded, zero-pad)
    const float* ap = Asrc + (size_t)(mt * 256 + arow) * lda + kb + aks;
#pragma unroll
    for (int j = 0; j < 4; ++j) {
      const int k = kb + aks + j * 4;
      float4 v = make_float4(0.f, 0.f, 0.f, 0.f);
      if (k + 4 <= lda) v = *reinterpret_cast<const float4*>(ap + j * 4);
      av[j * 4 + 0] = v.x; av[j * 4 + 1] = v.y;
      av[j * 4 + 2] = v.z; av[j * 4 + 3] = v.w;
    }
    // B: 32 k x 256 cols, 1 thread/ (col, k-half), 16 strided scalar loads
    const float* wp = W + (size_t)(kb + bkh * 16) * 1024 + bgcol;
#pragma unroll
    for (int j = 0; j < 16; ++j) {
      const int kg = kb + bkh * 16 + j;
      bv[j] = (kg < lda) ? wp[(size_t)j * 1024] : 0.0f;
    }
  };

  auto stage_write = [&](int b) {
    unsigned short* Ab = smem + b * LDSOFF;
    unsigned short* Bb = smem + 2 * LDSOFF + b * LDSOFF;
    u16x8 va0, va1, vb0, vb1;
#pragma unroll
    for (int j = 0; j < 8; ++j) {
      va0[j] = f2bf(av[j]);     va1[j] = f2bf(av[8 + j]);
      vb0[j] = f2bf(bv[j]);     vb1[j] = f2bf(bv[8 + j]);
    }
    *reinterpret_cast<u16x8*>(&Ab[arow * KPAD + aks])          = va0;
    *reinterpret_cast<u16x8*>(&Ab[arow * KPAD + aks + 8])      = va1;
    *reinterpret_cast<u16x8*>(&Bb[bcol * KPAD + bkh * 16])     = vb0;
    *reinterpret_cast<u16x8*>(&Bb[bcol * KPAD + bkh * 16 + 8]) = vb1;
  };

  // ---- prologue ----
  stage_load(0);
  stage_write(0);
  __syncthreads();

  // ---- main K loop: 1 barrier/stage, loads issued before MFMAs ----
  for (int s = 0; s < NSTAGE; ++s) {
    const int cur = s & 1;
    if (s + 1 < NSTAGE) stage_load(s + 1);     // issue globals early

    const unsigned short* Ab = smem + cur * LDSOFF;
    const unsigned short* Bb = smem + 2 * LDSOFF + cur * LDSOFF;
#pragma unroll
    for (int kk = 0; kk < 2; ++kk) {
      bf16x8 afr[2], bfr[4];
#pragma unroll
      for (int m = 0; m < 2; ++m)
        afr[m] = *reinterpret_cast<const bf16x8*>(
            &Ab[(wr * 64 + m * 32 + l31) * KPAD + kk * 16 + hl * 8]);
#pragma unroll
      for (int n = 0; n < 4; ++n)
        bfr[n] = *reinterpret_cast<const bf16x8*>(
            &Bb[(wc * 128 + n * 32 + l31) * KPAD + kk * 16 + hl * 8]);
#pragma unroll
      for (int m = 0; m < 2; ++m)
#pragma unroll
        for (int n = 0; n < 4; ++n)
          acc[m][n] = __builtin_amdgcn_mfma_f32_32x32x16_bf16(
              afr[m], bfr[n], acc[m][n], 0, 0, 0);
    }

    if (s + 1 < NSTAGE) stage_write(cur ^ 1);  // cvt + ds_write after MFMAs
    __syncthreads();
  }

  // ---- epilogue: lane-local gate combine ----
  // D layout (32x32): col = lane&31, row = (reg&3) + 8*(reg>>2) + 4*(lane>>5)
  const size_t HTOT = (size_t)NROWS * HDIM;
#pragma unroll
  for (int m = 0; m < 2; ++m) {
    const int rb = mt * 256 + wr * 64 + m * 32 + hl * 4;
#pragma unroll
    for (int reg = 0; reg < 16; ++reg) {
      const int r = rb + (reg & 3) + 8 * (reg >> 2);
      const float pi = acc[m][0][reg] + bias[0];
      const float pf = acc[m][1][reg] + bias[1];
      const float pg = acc[m][2][reg] + bias[2];
      const float po = acc[m][3][reg] + bias[3];
      const float Cv = Cin[(size_t)r * HDIM + ch];
      const float ig = sigm(pi);
      const float fg = sigm(pf);
      const float gg = tanh_fast(pg);
      const float og = sigm(po);
      const float co = fg * Cv + ig * gg;
      const float ho = og * tanh_fast(co);
      out[(size_t)r * HDIM + ch]        = co;
      out[HTOT + (size_t)r * HDIM + ch] = ho;
    }
  }
}

extern "C" void kernel_launch(void* const* d_in, const int* in_sizes, int n_in,
                              void* d_out, int out_size, void* d_ws, size_t ws_size,
                              hipStream_t stream) {
  const float* x  = (const float*)d_in[0];
  const float* C  = (const float*)d_in[1];
  const float* h  = (const float*)d_in[2];
  const float* Wx = (const float*)d_in[3];
  const float* Wh = (const float*)d_in[4];
  const float* bx = (const float*)d_in[5];
  const float* bh = (const float*)d_in[6];
  float* o = (float*)d_out;

  // grid: 512 M-tiles x 4 N-tiles = 2048 blocks, XCD-swizzled in-kernel
  lstm_fused<<<dim3(2048), dim3(512), 0, stream>>>(x, C, h, Wx, Wh, bx, bh, o);
}